// Round 4
// baseline (491.330 us; speedup 1.0000x reference)
//
#include <hip/hip_runtime.h>
#include <hip/hip_bf16.h>
#include <math.h>

typedef __attribute__((ext_vector_type(4))) float  f32x4;
typedef __attribute__((ext_vector_type(8))) __bf16 bf16x8;

#define LN_EPS 1e-6f

// ---------- small math helpers ----------
__device__ __forceinline__ float sigf(float v){ return 1.f / (1.f + __expf(-v)); }
__device__ __forceinline__ float tanh_f(float v){
  float t = __expf(-2.f * fabsf(v));
  float r = (1.f - t) / (1.f + t);
  return copysignf(r, v);
}
__device__ __forceinline__ float wave_sum(float v){
  #pragma unroll
  for(int m = 1; m < 64; m <<= 1) v += __shfl_xor(v, m, 64);
  return v;
}

// pack two f32 -> two bf16 (RNE), low word = a
__device__ __forceinline__ unsigned int pk_bf16(float a, float b){
  union { float f; unsigned int u; } ua, ub;
  ua.f = a; ub.f = b;
  unsigned int x = (ua.u + 0x7FFFu + ((ua.u >> 16) & 1u)) >> 16;
  unsigned int y = (ub.u + 0x7FFFu + ((ub.u >> 16) & 1u)) >> 16;
  return x | (y << 16);
}

// ---------- GEMM staging: f32 global tile (NROWS x 64) -> bf16 LDS with XOR swizzle ----------
// LDS layout: row-major [NROWS][64] bf16 (128 B/row), byte ^= (row&7)<<4
template<int NROWS, int NTHR>
__device__ __forceinline__ void stage_tile(const float* __restrict__ src, int row_stride,
                                           unsigned short* lds, int tid){
  constexpr int PER = (NROWS * 16) / NTHR;   // float4's per thread
  #pragma unroll
  for(int s = 0; s < PER; ++s){
    int fi  = tid + s * NTHR;
    int row = fi >> 4, kf = fi & 15;
    float4 v = *(reinterpret_cast<const float4*>(src + row * row_stride) + kf);
    unsigned int lo = pk_bf16(v.x, v.y), hi = pk_bf16(v.z, v.w);
    int byte = ((row << 7) + (kf << 3)) ^ ((row & 7) << 4);
    uint2 u; u.x = lo; u.y = hi;
    *reinterpret_cast<uint2*>(reinterpret_cast<char*>(lds) + byte) = u;
  }
}

// read one 16x32 MFMA operand fragment: lane holds row=(lane&15)+row0, k = ks + (lane>>4)*8 .. +7
__device__ __forceinline__ bf16x8 read_frag(const unsigned short* lds, int row, int ks, int lane){
  int byte = ((row << 7) + ((ks + ((lane >> 4) << 3)) << 1)) ^ ((row & 7) << 4);
  return *reinterpret_cast<const bf16x8*>(reinterpret_cast<const char*>(lds) + byte);
}

// =====================================================================
// K1: v = [x | h | hyper_h] @ [hc_Wih | hc_Whh]^T + hc_bih   (512 x 1024, K=4352)
// 32x32 tile, 256 thr (4 waves, 2x2, wave tile 16x16), BK=64 -> 512 blocks (2/CU)
// =====================================================================
__global__ __launch_bounds__(256, 4) void k1_hyper_gemm(
    const float* __restrict__ x, const float* __restrict__ h,
    const float* __restrict__ hyper_h, const float* __restrict__ hc_Wih,
    const float* __restrict__ hc_Whh, const float* __restrict__ hc_bih,
    float* __restrict__ vout){
  __shared__ unsigned short Ab[32 * 64];
  __shared__ unsigned short Bb[32 * 64];
  int tid = threadIdx.x, lane = tid & 63, w = tid >> 6;
  int wr = w >> 1, wc = w & 1;
  int n0 = blockIdx.x * 32, m0 = blockIdx.y * 32;
  f32x4 acc = {0.f, 0.f, 0.f, 0.f};

  #pragma unroll 1
  for(int k0 = 0; k0 < 4352; k0 += 64){
    const float* as; int ast;
    if(k0 < 2048)      { as = x       + m0 * 2048 + k0;          ast = 2048; }
    else if(k0 < 4096) { as = h       + m0 * 2048 + (k0 - 2048); ast = 2048; }
    else               { as = hyper_h + m0 * 256  + (k0 - 4096); ast = 256;  }
    const float* bs; int bst;
    if(k0 < 4096)      { bs = hc_Wih  + n0 * 4096 + k0;          bst = 4096; }
    else               { bs = hc_Whh  + n0 * 256  + (k0 - 4096); bst = 256;  }
    __syncthreads();
    stage_tile<32, 256>(as, ast, Ab, tid);
    stage_tile<32, 256>(bs, bst, Bb, tid);
    __syncthreads();
    #pragma unroll
    for(int ks = 0; ks < 64; ks += 32){
      bf16x8 af = read_frag(Ab, wr * 16 + (lane & 15), ks, lane);
      bf16x8 bf = read_frag(Bb, wc * 16 + (lane & 15), ks, lane);
      acc = __builtin_amdgcn_mfma_f32_16x16x32_bf16(af, bf, acc, 0, 0, 0);
    }
  }
  int n = n0 + wc * 16 + (lane & 15);
  float bv = hc_bih[n];
  #pragma unroll
  for(int r = 0; r < 4; ++r){
    int m = m0 + wr * 16 + (lane >> 4) * 4 + r;
    vout[m * 1024 + n] = acc[r] + bv;
  }
}

// =====================================================================
// K2: hyper LN + hyper LSTM cell. 1 wave per batch row. Writes new_hyper_h/new_hyper_c to d_out.
// =====================================================================
__global__ __launch_bounds__(256) void k2_hyper_cell(
    const float* __restrict__ v, const float* __restrict__ hyper_c,
    const float* __restrict__ lng, const float* __restrict__ lnb,
    const float* __restrict__ lncg, const float* __restrict__ lncb,
    float* __restrict__ out){
  int tid = threadIdx.x, lane = tid & 63, w = tid >> 6;
  int b = blockIdx.x * 4 + w;
  const float* vr = v + b * 1024;
  float vn[4][4];
  #pragma unroll
  for(int g = 0; g < 4; ++g){
    float vv[4], s = 0.f;
    #pragma unroll
    for(int q = 0; q < 4; ++q){ vv[q] = vr[g * 256 + lane + 64 * q]; s += vv[q]; }
    float mean = wave_sum(s) * (1.f / 256.f);
    float sse = 0.f;
    #pragma unroll
    for(int q = 0; q < 4; ++q){ float d = vv[q] - mean; sse += d * d; }
    float inv = 1.f / (sqrtf(wave_sum(sse) * (1.f / 255.f)) + LN_EPS);
    #pragma unroll
    for(int q = 0; q < 4; ++q){
      int e = lane + 64 * q;
      vn[g][q] = lng[g * 256 + e] * (vv[q] - mean) * inv + lnb[g * 256 + e];
    }
  }
  float ncr[4], os[4], s2 = 0.f;
  #pragma unroll
  for(int q = 0; q < 4; ++q){
    float hc = hyper_c[b * 256 + lane + 64 * q];
    float hi = vn[0][q], hf = vn[1][q] + 1.f, hg = vn[2][q], ho = vn[3][q];
    ncr[q] = hc * sigf(hf) + sigf(hi) * tanh_f(hg);
    os[q]  = sigf(ho);
    s2 += ncr[q];
  }
  float mean2 = wave_sum(s2) * (1.f / 256.f);
  float sse2 = 0.f;
  #pragma unroll
  for(int q = 0; q < 4; ++q){ float d = ncr[q] - mean2; sse2 += d * d; }
  float inv2 = 1.f / (sqrtf(wave_sum(sse2) * (1.f / 255.f)) + LN_EPS);
  #pragma unroll
  for(int q = 0; q < 4; ++q){
    int e = lane + 64 * q;
    float ncn = lncg[e] * (ncr[q] - mean2) * inv2 + lncb[e];
    out[2097152 + b * 256 + e] = tanh_f(ncn) * os[q];  // new_hyper_h
    out[2228224 + b * 256 + e] = ncn;                  // new_hyper_c
  }
}

// =====================================================================
// K3: P = nhh @ [Wph|Wpx|Wpb]^T + [bph|bpx|0]   (512 x 768, K=256)
// =====================================================================
__global__ __launch_bounds__(256, 2) void k3_pmat(
    const float* __restrict__ nhh, const float* __restrict__ Wph,
    const float* __restrict__ Wpx, const float* __restrict__ Wpb,
    const float* __restrict__ bph, const float* __restrict__ bpx,
    float* __restrict__ P){
  __shared__ unsigned short Ab[64 * 64];
  __shared__ unsigned short Bb[64 * 64];
  int tid = threadIdx.x, lane = tid & 63, w = tid >> 6;
  int wr = w >> 1, wc = w & 1;
  int n0 = blockIdx.x * 64, m0 = blockIdx.y * 64;
  int j3 = n0 >> 8, jr0 = n0 & 255;
  const float* W = (j3 == 0) ? Wph : (j3 == 1) ? Wpx : Wpb;
  f32x4 acc[2][2];
  const f32x4 zf = {0.f, 0.f, 0.f, 0.f};
  #pragma unroll
  for(int i = 0; i < 2; ++i){ acc[i][0] = zf; acc[i][1] = zf; }

  #pragma unroll 1
  for(int k0 = 0; k0 < 256; k0 += 64){
    __syncthreads();
    stage_tile<64, 256>(nhh + m0 * 256 + k0, 256, Ab, tid);
    stage_tile<64, 256>(W + jr0 * 256 + k0, 256, Bb, tid);
    __syncthreads();
    #pragma unroll
    for(int ks = 0; ks < 64; ks += 32){
      bf16x8 af[2], bfr[2];
      #pragma unroll
      for(int i = 0; i < 2; ++i) af[i]  = read_frag(Ab, wr * 32 + i * 16 + (lane & 15), ks, lane);
      #pragma unroll
      for(int j = 0; j < 2; ++j) bfr[j] = read_frag(Bb, wc * 32 + j * 16 + (lane & 15), ks, lane);
      #pragma unroll
      for(int i = 0; i < 2; ++i){
        #pragma unroll
        for(int j = 0; j < 2; ++j)
          acc[i][j] = __builtin_amdgcn_mfma_f32_16x16x32_bf16(af[i], bfr[j], acc[i][j], 0, 0, 0);
      }
    }
  }
  #pragma unroll
  for(int j = 0; j < 2; ++j){
    int cj = jr0 + wc * 32 + j * 16 + (lane & 15);
    float bv = (j3 == 0) ? bph[cj] : (j3 == 1) ? bpx[cj] : 0.f;
    int n = n0 + wc * 32 + j * 16 + (lane & 15);
    #pragma unroll
    for(int i = 0; i < 2; ++i){
      #pragma unroll
      for(int r = 0; r < 4; ++r){
        int m = m0 + wr * 32 + i * 16 + (lane >> 4) * 4 + r;
        P[m * 768 + n] = acc[i][j][r] + bv;
      }
    }
  }
}

// =====================================================================
// K4: gates = (x@Wih^T)*zx + (h@Whh^T)*zh + bias + zb
// 64x128 tile, 256 thr (4 waves, 2x2, wave tile 32x64), BK=64 -> 512 blocks (2/CU).
// XCD swizzle: each XCD owns a contiguous n-range (weight panels fetched once per L2);
// consecutive blocks within an XCD share the same weight panel (8 m-tiles each).
// =====================================================================
__global__ __launch_bounds__(256, 4) void k4_gates(
    const float* __restrict__ x, const float* __restrict__ h,
    const float* __restrict__ Wih, const float* __restrict__ Whh,
    const float* __restrict__ bias, const float* __restrict__ P,
    const float* __restrict__ Wsh, const float* __restrict__ Wsx,
    const float* __restrict__ Wsb, float* __restrict__ gates){
  __shared__ unsigned short Ab[64 * 64];
  __shared__ unsigned short Bb[128 * 64];
  int tid = threadIdx.x, lane = tid & 63, w = tid >> 6;
  int wr = w >> 1, wc = w & 1;          // 2x2 wave grid, wave tile 32x64
  int fid = blockIdx.x;                 // 512 blocks
  int xcd = fid & 7, idx = fid >> 3;    // idx 0..63
  int nt = xcd * 8 + (idx >> 3);        // n-tile 0..63 (contiguous 8 per XCD)
  int mt = idx & 7;                     // m-tile 0..7
  int n0 = nt << 7, m0 = mt << 6;
  int g = n0 >> 11, hc0 = n0 & 2047;

  f32x4 accG[2][4], accT[2][4], accU[2][4];
  const f32x4 zf = {0.f, 0.f, 0.f, 0.f};

  auto step = [&](const float* as, int ast, const float* bs, int bst, f32x4 (&acc)[2][4]){
    __syncthreads();
    stage_tile<64, 256>(as, ast, Ab, tid);
    stage_tile<128, 256>(bs, bst, Bb, tid);
    __syncthreads();
    #pragma unroll
    for(int ks = 0; ks < 64; ks += 32){
      bf16x8 af[2], bfr[4];
      #pragma unroll
      for(int i = 0; i < 2; ++i) af[i]  = read_frag(Ab, wr * 32 + i * 16 + (lane & 15), ks, lane);
      #pragma unroll
      for(int j = 0; j < 4; ++j) bfr[j] = read_frag(Bb, wc * 64 + j * 16 + (lane & 15), ks, lane);
      #pragma unroll
      for(int i = 0; i < 2; ++i){
        #pragma unroll
        for(int j = 0; j < 4; ++j)
          acc[i][j] = __builtin_amdgcn_mfma_f32_16x16x32_bf16(af[i], bfr[j], acc[i][j], 0, 0, 0);
      }
    }
  };

  #pragma unroll
  for(int i = 0; i < 2; ++i){
    #pragma unroll
    for(int j = 0; j < 4; ++j){ accG[i][j] = zf; accT[i][j] = zf; accU[i][j] = zf; }
  }

  // accG = zh tile
  step(P + m0 * 768 + g * 64, 768, Wsh + (g * 2048 + hc0) * 64, 64, accG);
  // accT = h @ Whh^T tile
  #pragma unroll 1
  for(int k0 = 0; k0 < 2048; k0 += 64)
    step(h + m0 * 2048 + k0, 2048, Whh + n0 * 2048 + k0, 2048, accT);
  #pragma unroll
  for(int i = 0; i < 2; ++i){
    #pragma unroll
    for(int j = 0; j < 4; ++j){ accG[i][j] *= accT[i][j]; accT[i][j] = zf; }
  }
  // accT = zx tile
  step(P + m0 * 768 + 256 + g * 64, 768, Wsx + (g * 2048 + hc0) * 64, 64, accT);
  // accU = x @ Wih^T tile
  #pragma unroll 1
  for(int k0 = 0; k0 < 2048; k0 += 64)
    step(x + m0 * 2048 + k0, 2048, Wih + n0 * 2048 + k0, 2048, accU);
  #pragma unroll
  for(int i = 0; i < 2; ++i){
    #pragma unroll
    for(int j = 0; j < 4; ++j){ accG[i][j] += accT[i][j] * accU[i][j]; accT[i][j] = zf; }
  }
  // accT = zb tile
  step(P + m0 * 768 + 512 + g * 64, 768, Wsb + (g * 2048 + hc0) * 64, 64, accT);

  // epilogue: + bias (the +1.0 on gate f pre-LN is a no-op under LN mean-subtraction)
  #pragma unroll
  for(int j = 0; j < 4; ++j){
    int n = n0 + wc * 64 + j * 16 + (lane & 15);
    float bv = bias[n];
    #pragma unroll
    for(int i = 0; i < 2; ++i){
      #pragma unroll
      for(int r = 0; r < 4; ++r){
        int m = m0 + wr * 32 + i * 16 + (lane >> 4) * 4 + r;
        gates[m * 8192 + n] = accG[i][j][r] + accT[i][j][r] + bv;
      }
    }
  }
}

// =====================================================================
// K5: gate LN (wave per gate) + LSTM cell + c-LN. Writes new_h, new_c.
// =====================================================================
__global__ __launch_bounds__(256) void k5_cell(
    const float* __restrict__ gates, const float* __restrict__ c,
    const float* __restrict__ lng, const float* __restrict__ lnb,
    const float* __restrict__ lncg, const float* __restrict__ lncb,
    float* __restrict__ out){
  __shared__ float G[4 * 2048];
  __shared__ float red[4];
  int tid = threadIdx.x, lane = tid & 63, w = tid >> 6;
  int b = blockIdx.x;
  const float* gr = gates + b * 8192 + w * 2048;
  float gv[32]; float s = 0.f;
  #pragma unroll
  for(int q = 0; q < 32; ++q){ gv[q] = gr[lane + 64 * q]; s += gv[q]; }
  float mean = wave_sum(s) * (1.f / 2048.f);
  float sse = 0.f;
  #pragma unroll
  for(int q = 0; q < 32; ++q){ float d = gv[q] - mean; sse += d * d; }
  float inv = 1.f / (sqrtf(wave_sum(sse) * (1.f / 2047.f)) + LN_EPS);
  #pragma unroll
  for(int q = 0; q < 32; ++q){
    int e = lane + 64 * q;
    G[w * 2048 + e] = lng[w * 2048 + e] * (gv[q] - mean) * inv + lnb[w * 2048 + e];
  }
  __syncthreads();
  float nc[8], os[8], s2 = 0.f;
  #pragma unroll
  for(int q = 0; q < 8; ++q){
    int e = tid + 256 * q;
    float iv = G[e], fv = G[2048 + e], gg = G[4096 + e], ov = G[6144 + e];
    float cc = c[b * 2048 + e];
    nc[q] = cc * sigf(fv) + sigf(iv) * tanh_f(gg);
    os[q] = sigf(ov);
    s2 += nc[q];
  }
  s2 = wave_sum(s2);
  if(lane == 0) red[w] = s2;
  __syncthreads();
  float mean2 = (red[0] + red[1] + red[2] + red[3]) * (1.f / 2048.f);
  float sse2 = 0.f;
  #pragma unroll
  for(int q = 0; q < 8; ++q){ float d = nc[q] - mean2; sse2 += d * d; }
  sse2 = wave_sum(sse2);
  __syncthreads();
  if(lane == 0) red[w] = sse2;
  __syncthreads();
  float inv2 = 1.f / (sqrtf((red[0] + red[1] + red[2] + red[3]) * (1.f / 2047.f)) + LN_EPS);
  #pragma unroll
  for(int q = 0; q < 8; ++q){
    int e = tid + 256 * q;
    float ncn = lncg[e] * (nc[q] - mean2) * inv2 + lncb[e];
    out[b * 2048 + e]           = tanh_f(ncn) * os[q];  // new_h
    out[1048576 + b * 2048 + e] = ncn;                  // new_c
  }
}

// =====================================================================
extern "C" void kernel_launch(void* const* d_in, const int* in_sizes, int n_in,
                              void* d_out, int out_size, void* d_ws, size_t ws_size,
                              hipStream_t stream){
  const float* x        = (const float*)d_in[0];
  const float* h        = (const float*)d_in[1];
  const float* c        = (const float*)d_in[2];
  const float* hyper_h  = (const float*)d_in[3];
  const float* hyper_c  = (const float*)d_in[4];
  const float* hc_Wih   = (const float*)d_in[5];
  const float* hc_bih   = (const float*)d_in[6];
  const float* hc_Whh   = (const float*)d_in[7];
  const float* hc_lng   = (const float*)d_in[8];
  const float* hc_lnb   = (const float*)d_in[9];
  const float* hc_lncg  = (const float*)d_in[10];
  const float* hc_lncb  = (const float*)d_in[11];
  const float* Wph      = (const float*)d_in[12];
  const float* bph      = (const float*)d_in[13];
  const float* Wpx      = (const float*)d_in[14];
  const float* bpx      = (const float*)d_in[15];
  const float* Wpb      = (const float*)d_in[16];
  const float* Wsh      = (const float*)d_in[17];
  const float* Wsx      = (const float*)d_in[18];
  const float* Wsb      = (const float*)d_in[19];
  const float* Wih      = (const float*)d_in[20];
  const float* Whh      = (const float*)d_in[21];
  const float* bias     = (const float*)d_in[22];
  const float* ln_g     = (const float*)d_in[23];
  const float* ln_b     = (const float*)d_in[24];
  const float* lnc_g    = (const float*)d_in[25];
  const float* lnc_b    = (const float*)d_in[26];

  float* out = (float*)d_out;
  float* ws  = (float*)d_ws;
  float* ws_v     = ws;                 // 512*1024
  float* ws_P     = ws + 524288;        // 512*768
  float* ws_gates = ws + 917504;        // 512*8192
  const float* nhh = out + 2097152;     // new_hyper_h region of d_out

  k1_hyper_gemm<<<dim3(32, 16), 256, 0, stream>>>(x, h, hyper_h, hc_Wih, hc_Whh, hc_bih, ws_v);
  k2_hyper_cell<<<128, 256, 0, stream>>>(ws_v, hyper_c, hc_lng, hc_lnb, hc_lncg, hc_lncb, out);
  k3_pmat<<<dim3(12, 8), 256, 0, stream>>>(nhh, Wph, Wpx, Wpb, bph, bpx, ws_P);
  k4_gates<<<512, 256, 0, stream>>>(x, h, Wih, Whh, bias, ws_P, Wsh, Wsx, Wsb, ws_gates);
  k5_cell<<<512, 256, 0, stream>>>(ws_gates, c, ln_g, ln_b, lnc_g, lnc_b, out);
}

// Round 5
// 170.182 us; speedup vs baseline: 2.8871x; 2.8871x over previous
//
#include <hip/hip_runtime.h>
#include <hip/hip_bf16.h>
#include <math.h>

typedef __attribute__((ext_vector_type(4))) float  f32x4;
typedef __attribute__((ext_vector_type(8))) __bf16 bf16x8;

#define LN_EPS 1e-6f

// ---------- small math helpers ----------
__device__ __forceinline__ float sigf(float v){ return 1.f / (1.f + __expf(-v)); }
__device__ __forceinline__ float tanh_f(float v){
  float t = __expf(-2.f * fabsf(v));
  float r = (1.f - t) / (1.f + t);
  return copysignf(r, v);
}
__device__ __forceinline__ float wave_sum(float v){
  #pragma unroll
  for(int m = 1; m < 64; m <<= 1) v += __shfl_xor(v, m, 64);
  return v;
}

// pack two f32 -> two bf16 (RNE), low word = a
__device__ __forceinline__ unsigned int pk_bf16(float a, float b){
  union { float f; unsigned int u; } ua, ub;
  ua.f = a; ub.f = b;
  unsigned int x = (ua.u + 0x7FFFu + ((ua.u >> 16) & 1u)) >> 16;
  unsigned int y = (ub.u + 0x7FFFu + ((ub.u >> 16) & 1u)) >> 16;
  return x | (y << 16);
}

// ---------- GEMM staging: f32 global tile (NROWS x 64) -> bf16 LDS with XOR swizzle ----------
// LDS layout: row-major [NROWS][64] bf16 (128 B/row), byte ^= (row&7)<<4
template<int NROWS, int NTHR>
__device__ __forceinline__ void stage_tile(const float* __restrict__ src, int row_stride,
                                           unsigned short* lds, int tid){
  constexpr int PER = (NROWS * 16) / NTHR;   // float4's per thread
  #pragma unroll
  for(int s = 0; s < PER; ++s){
    int fi  = tid + s * NTHR;
    int row = fi >> 4, kf = fi & 15;
    float4 v = *(reinterpret_cast<const float4*>(src + row * row_stride) + kf);
    unsigned int lo = pk_bf16(v.x, v.y), hi = pk_bf16(v.z, v.w);
    int byte = ((row << 7) + (kf << 3)) ^ ((row & 7) << 4);
    uint2 u; u.x = lo; u.y = hi;
    *reinterpret_cast<uint2*>(reinterpret_cast<char*>(lds) + byte) = u;
  }
}

// read one 16x32 MFMA operand fragment: lane holds row=(lane&15)+row0, k = ks + (lane>>4)*8 .. +7
__device__ __forceinline__ bf16x8 read_frag(const unsigned short* lds, int row, int ks, int lane){
  int byte = ((row << 7) + ((ks + ((lane >> 4) << 3)) << 1)) ^ ((row & 7) << 4);
  return *reinterpret_cast<const bf16x8*>(reinterpret_cast<const char*>(lds) + byte);
}

// =====================================================================
// K1: v = [x | h | hyper_h] @ [hc_Wih | hc_Whh]^T + hc_bih   (512 x 1024, K=4352)
// 32x32 tile, 256 thr (4 waves, 2x2, wave tile 16x16), BK=64 -> 512 blocks (2/CU)
// =====================================================================
__global__ __launch_bounds__(256, 2) void k1_hyper_gemm(
    const float* __restrict__ x, const float* __restrict__ h,
    const float* __restrict__ hyper_h, const float* __restrict__ hc_Wih,
    const float* __restrict__ hc_Whh, const float* __restrict__ hc_bih,
    float* __restrict__ vout){
  __shared__ unsigned short Ab[32 * 64];
  __shared__ unsigned short Bb[32 * 64];
  int tid = threadIdx.x, lane = tid & 63, w = tid >> 6;
  int wr = w >> 1, wc = w & 1;
  int n0 = blockIdx.x * 32, m0 = blockIdx.y * 32;
  f32x4 acc = {0.f, 0.f, 0.f, 0.f};

  #pragma unroll 1
  for(int k0 = 0; k0 < 4352; k0 += 64){
    const float* as; int ast;
    if(k0 < 2048)      { as = x       + m0 * 2048 + k0;          ast = 2048; }
    else if(k0 < 4096) { as = h       + m0 * 2048 + (k0 - 2048); ast = 2048; }
    else               { as = hyper_h + m0 * 256  + (k0 - 4096); ast = 256;  }
    const float* bs; int bst;
    if(k0 < 4096)      { bs = hc_Wih  + n0 * 4096 + k0;          bst = 4096; }
    else               { bs = hc_Whh  + n0 * 256  + (k0 - 4096); bst = 256;  }
    __syncthreads();
    stage_tile<32, 256>(as, ast, Ab, tid);
    stage_tile<32, 256>(bs, bst, Bb, tid);
    __syncthreads();
    #pragma unroll
    for(int ks = 0; ks < 64; ks += 32){
      bf16x8 af = read_frag(Ab, wr * 16 + (lane & 15), ks, lane);
      bf16x8 bf = read_frag(Bb, wc * 16 + (lane & 15), ks, lane);
      acc = __builtin_amdgcn_mfma_f32_16x16x32_bf16(af, bf, acc, 0, 0, 0);
    }
  }
  int n = n0 + wc * 16 + (lane & 15);
  float bv = hc_bih[n];
  #pragma unroll
  for(int r = 0; r < 4; ++r){
    int m = m0 + wr * 16 + (lane >> 4) * 4 + r;
    vout[m * 1024 + n] = acc[r] + bv;
  }
}

// =====================================================================
// K2: hyper LN + hyper LSTM cell. 1 wave per batch row. Writes new_hyper_h/new_hyper_c to d_out.
// =====================================================================
__global__ __launch_bounds__(256) void k2_hyper_cell(
    const float* __restrict__ v, const float* __restrict__ hyper_c,
    const float* __restrict__ lng, const float* __restrict__ lnb,
    const float* __restrict__ lncg, const float* __restrict__ lncb,
    float* __restrict__ out){
  int tid = threadIdx.x, lane = tid & 63, w = tid >> 6;
  int b = blockIdx.x * 4 + w;
  const float* vr = v + b * 1024;
  float vn[4][4];
  #pragma unroll
  for(int g = 0; g < 4; ++g){
    float vv[4], s = 0.f;
    #pragma unroll
    for(int q = 0; q < 4; ++q){ vv[q] = vr[g * 256 + lane + 64 * q]; s += vv[q]; }
    float mean = wave_sum(s) * (1.f / 256.f);
    float sse = 0.f;
    #pragma unroll
    for(int q = 0; q < 4; ++q){ float d = vv[q] - mean; sse += d * d; }
    float inv = 1.f / (sqrtf(wave_sum(sse) * (1.f / 255.f)) + LN_EPS);
    #pragma unroll
    for(int q = 0; q < 4; ++q){
      int e = lane + 64 * q;
      vn[g][q] = lng[g * 256 + e] * (vv[q] - mean) * inv + lnb[g * 256 + e];
    }
  }
  float ncr[4], os[4], s2 = 0.f;
  #pragma unroll
  for(int q = 0; q < 4; ++q){
    float hc = hyper_c[b * 256 + lane + 64 * q];
    float hi = vn[0][q], hf = vn[1][q] + 1.f, hg = vn[2][q], ho = vn[3][q];
    ncr[q] = hc * sigf(hf) + sigf(hi) * tanh_f(hg);
    os[q]  = sigf(ho);
    s2 += ncr[q];
  }
  float mean2 = wave_sum(s2) * (1.f / 256.f);
  float sse2 = 0.f;
  #pragma unroll
  for(int q = 0; q < 4; ++q){ float d = ncr[q] - mean2; sse2 += d * d; }
  float inv2 = 1.f / (sqrtf(wave_sum(sse2) * (1.f / 255.f)) + LN_EPS);
  #pragma unroll
  for(int q = 0; q < 4; ++q){
    int e = lane + 64 * q;
    float ncn = lncg[e] * (ncr[q] - mean2) * inv2 + lncb[e];
    out[2097152 + b * 256 + e] = tanh_f(ncn) * os[q];  // new_hyper_h
    out[2228224 + b * 256 + e] = ncn;                  // new_hyper_c
  }
}

// =====================================================================
// K3: P = nhh @ [Wph|Wpx|Wpb]^T + [bph|bpx|0]   (512 x 768, K=256)
// =====================================================================
__global__ __launch_bounds__(256, 2) void k3_pmat(
    const float* __restrict__ nhh, const float* __restrict__ Wph,
    const float* __restrict__ Wpx, const float* __restrict__ Wpb,
    const float* __restrict__ bph, const float* __restrict__ bpx,
    float* __restrict__ P){
  __shared__ unsigned short Ab[64 * 64];
  __shared__ unsigned short Bb[64 * 64];
  int tid = threadIdx.x, lane = tid & 63, w = tid >> 6;
  int wr = w >> 1, wc = w & 1;
  int n0 = blockIdx.x * 64, m0 = blockIdx.y * 64;
  int j3 = n0 >> 8, jr0 = n0 & 255;
  const float* W = (j3 == 0) ? Wph : (j3 == 1) ? Wpx : Wpb;
  f32x4 acc[2][2];
  const f32x4 zf = {0.f, 0.f, 0.f, 0.f};
  #pragma unroll
  for(int i = 0; i < 2; ++i){ acc[i][0] = zf; acc[i][1] = zf; }

  #pragma unroll 1
  for(int k0 = 0; k0 < 256; k0 += 64){
    __syncthreads();
    stage_tile<64, 256>(nhh + m0 * 256 + k0, 256, Ab, tid);
    stage_tile<64, 256>(W + jr0 * 256 + k0, 256, Bb, tid);
    __syncthreads();
    #pragma unroll
    for(int ks = 0; ks < 64; ks += 32){
      bf16x8 af[2], bfr[2];
      #pragma unroll
      for(int i = 0; i < 2; ++i) af[i]  = read_frag(Ab, wr * 32 + i * 16 + (lane & 15), ks, lane);
      #pragma unroll
      for(int j = 0; j < 2; ++j) bfr[j] = read_frag(Bb, wc * 32 + j * 16 + (lane & 15), ks, lane);
      #pragma unroll
      for(int i = 0; i < 2; ++i){
        #pragma unroll
        for(int j = 0; j < 2; ++j)
          acc[i][j] = __builtin_amdgcn_mfma_f32_16x16x32_bf16(af[i], bfr[j], acc[i][j], 0, 0, 0);
      }
    }
  }
  #pragma unroll
  for(int j = 0; j < 2; ++j){
    int cj = jr0 + wc * 32 + j * 16 + (lane & 15);
    float bv = (j3 == 0) ? bph[cj] : (j3 == 1) ? bpx[cj] : 0.f;
    int n = n0 + wc * 32 + j * 16 + (lane & 15);
    #pragma unroll
    for(int i = 0; i < 2; ++i){
      #pragma unroll
      for(int r = 0; r < 4; ++r){
        int m = m0 + wr * 32 + i * 16 + (lane >> 4) * 4 + r;
        P[m * 768 + n] = acc[i][j][r] + bv;
      }
    }
  }
}

// =====================================================================
// K4: gates = (x@Wih^T)*zx + (h@Whh^T)*zh + bias + zb
// 64x128 tile, 256 thr (4 waves 2x2, wave tile 32x64), BK=64 -> 512 blocks (2/CU).
// Only TWO accumulator sets live at any time; xh*zx parked in LDS (per-thread
// private slot -> no barrier needed). launch_bounds(256,2): VGPR cap 256, no spill.
// =====================================================================
__global__ __launch_bounds__(256, 2) void k4_gates(
    const float* __restrict__ x, const float* __restrict__ h,
    const float* __restrict__ Wih, const float* __restrict__ Whh,
    const float* __restrict__ bias, const float* __restrict__ P,
    const float* __restrict__ Wsh, const float* __restrict__ Wsx,
    const float* __restrict__ Wsb, float* __restrict__ gates){
  __shared__ unsigned short Ab[64 * 64];     // 8 KB
  __shared__ unsigned short Bb[128 * 64];    // 16 KB
  __shared__ float Park[32 * 256];           // 32 KB: [comp][tid], conflict-free
  int tid = threadIdx.x, lane = tid & 63, w = tid >> 6;
  int wr = w >> 1, wc = w & 1;          // 2x2 wave grid, wave tile 32x64
  int fid = blockIdx.x;                 // 512 blocks
  int xcd = fid & 7, idx = fid >> 3;    // idx 0..63
  int nt = xcd * 8 + (idx >> 3);        // n-tile 0..63 (contiguous 8 per XCD)
  int mt = idx & 7;                     // m-tile 0..7
  int n0 = nt << 7, m0 = mt << 6;
  int g = n0 >> 11, hc0 = n0 & 2047;

  f32x4 accT[2][4], accU[2][4];
  const f32x4 zf = {0.f, 0.f, 0.f, 0.f};

  auto step = [&](const float* as, int ast, const float* bs, int bst, f32x4 (&acc)[2][4]){
    __syncthreads();
    stage_tile<64, 256>(as, ast, Ab, tid);
    stage_tile<128, 256>(bs, bst, Bb, tid);
    __syncthreads();
    #pragma unroll
    for(int ks = 0; ks < 64; ks += 32){
      bf16x8 af[2], bfr[4];
      #pragma unroll
      for(int i = 0; i < 2; ++i) af[i]  = read_frag(Ab, wr * 32 + i * 16 + (lane & 15), ks, lane);
      #pragma unroll
      for(int j = 0; j < 4; ++j) bfr[j] = read_frag(Bb, wc * 64 + j * 16 + (lane & 15), ks, lane);
      #pragma unroll
      for(int i = 0; i < 2; ++i){
        #pragma unroll
        for(int j = 0; j < 4; ++j)
          acc[i][j] = __builtin_amdgcn_mfma_f32_16x16x32_bf16(af[i], bfr[j], acc[i][j], 0, 0, 0);
      }
    }
  };

  #pragma unroll
  for(int i = 0; i < 2; ++i){
    #pragma unroll
    for(int j = 0; j < 4; ++j){ accT[i][j] = zf; accU[i][j] = zf; }
  }

  // Phase 1: accT = zx tile (K=64 mini-GEMM)
  step(P + m0 * 768 + 256 + g * 64, 768, Wsx + (g * 2048 + hc0) * 64, 64, accT);
  // Phase 2: accU = x @ Wih^T tile (K=2048)
  #pragma unroll 1
  for(int k0 = 0; k0 < 2048; k0 += 64)
    step(x + m0 * 2048 + k0, 2048, Wih + n0 * 2048 + k0, 2048, accU);
  // park xh*zx into LDS (own slot: no cross-thread sharing, no barrier needed)
  #pragma unroll
  for(int i = 0; i < 2; ++i)
    #pragma unroll
    for(int j = 0; j < 4; ++j)
      #pragma unroll
      for(int r = 0; r < 4; ++r){
        Park[(((i << 2) + j) * 4 + r) * 256 + tid] = accT[i][j][r] * accU[i][j][r];
        accT[i][j][r] = 0.f; accU[i][j][r] = 0.f;
      }

  // Phase 3: accT = zh tile
  step(P + m0 * 768 + g * 64, 768, Wsh + (g * 2048 + hc0) * 64, 64, accT);
  // Phase 4: accU = h @ Whh^T tile (K=2048)
  #pragma unroll 1
  for(int k0 = 0; k0 < 2048; k0 += 64)
    step(h + m0 * 2048 + k0, 2048, Whh + n0 * 2048 + k0, 2048, accU);
  // accT = hh*zh + parked xh*zx  (result set), then zero accU for zb
  #pragma unroll
  for(int i = 0; i < 2; ++i)
    #pragma unroll
    for(int j = 0; j < 4; ++j)
      #pragma unroll
      for(int r = 0; r < 4; ++r){
        accT[i][j][r] = accT[i][j][r] * accU[i][j][r]
                      + Park[(((i << 2) + j) * 4 + r) * 256 + tid];
        accU[i][j][r] = 0.f;
      }

  // Phase 5: accU = zb tile
  step(P + m0 * 768 + 512 + g * 64, 768, Wsb + (g * 2048 + hc0) * 64, 64, accU);

  // epilogue: + bias (the +1.0 on gate f pre-LN is a no-op under LN mean-subtraction)
  #pragma unroll
  for(int j = 0; j < 4; ++j){
    int n = n0 + wc * 64 + j * 16 + (lane & 15);
    float bv = bias[n];
    #pragma unroll
    for(int i = 0; i < 2; ++i){
      #pragma unroll
      for(int r = 0; r < 4; ++r){
        int m = m0 + wr * 32 + i * 16 + (lane >> 4) * 4 + r;
        gates[m * 8192 + n] = accT[i][j][r] + accU[i][j][r] + bv;
      }
    }
  }
}

// =====================================================================
// K5: gate LN (wave per gate) + LSTM cell + c-LN. Writes new_h, new_c.
// =====================================================================
__global__ __launch_bounds__(256) void k5_cell(
    const float* __restrict__ gates, const float* __restrict__ c,
    const float* __restrict__ lng, const float* __restrict__ lnb,
    const float* __restrict__ lncg, const float* __restrict__ lncb,
    float* __restrict__ out){
  __shared__ float G[4 * 2048];
  __shared__ float red[4];
  int tid = threadIdx.x, lane = tid & 63, w = tid >> 6;
  int b = blockIdx.x;
  const float* gr = gates + b * 8192 + w * 2048;
  float gv[32]; float s = 0.f;
  #pragma unroll
  for(int q = 0; q < 32; ++q){ gv[q] = gr[lane + 64 * q]; s += gv[q]; }
  float mean = wave_sum(s) * (1.f / 2048.f);
  float sse = 0.f;
  #pragma unroll
  for(int q = 0; q < 32; ++q){ float d = gv[q] - mean; sse += d * d; }
  float inv = 1.f / (sqrtf(wave_sum(sse) * (1.f / 2047.f)) + LN_EPS);
  #pragma unroll
  for(int q = 0; q < 32; ++q){
    int e = lane + 64 * q;
    G[w * 2048 + e] = lng[w * 2048 + e] * (gv[q] - mean) * inv + lnb[w * 2048 + e];
  }
  __syncthreads();
  float nc[8], os[8], s2 = 0.f;
  #pragma unroll
  for(int q = 0; q < 8; ++q){
    int e = tid + 256 * q;
    float iv = G[e], fv = G[2048 + e], gg = G[4096 + e], ov = G[6144 + e];
    float cc = c[b * 2048 + e];
    nc[q] = cc * sigf(fv) + sigf(iv) * tanh_f(gg);
    os[q] = sigf(ov);
    s2 += nc[q];
  }
  s2 = wave_sum(s2);
  if(lane == 0) red[w] = s2;
  __syncthreads();
  float mean2 = (red[0] + red[1] + red[2] + red[3]) * (1.f / 2048.f);
  float sse2 = 0.f;
  #pragma unroll
  for(int q = 0; q < 8; ++q){ float d = nc[q] - mean2; sse2 += d * d; }
  sse2 = wave_sum(sse2);
  __syncthreads();
  if(lane == 0) red[w] = sse2;
  __syncthreads();
  float inv2 = 1.f / (sqrtf((red[0] + red[1] + red[2] + red[3]) * (1.f / 2047.f)) + LN_EPS);
  #pragma unroll
  for(int q = 0; q < 8; ++q){
    int e = tid + 256 * q;
    float ncn = lncg[e] * (nc[q] - mean2) * inv2 + lncb[e];
    out[b * 2048 + e]           = tanh_f(ncn) * os[q];  // new_h
    out[1048576 + b * 2048 + e] = ncn;                  // new_c
  }
}

// =====================================================================
extern "C" void kernel_launch(void* const* d_in, const int* in_sizes, int n_in,
                              void* d_out, int out_size, void* d_ws, size_t ws_size,
                              hipStream_t stream){
  const float* x        = (const float*)d_in[0];
  const float* h        = (const float*)d_in[1];
  const float* c        = (const float*)d_in[2];
  const float* hyper_h  = (const float*)d_in[3];
  const float* hyper_c  = (const float*)d_in[4];
  const float* hc_Wih   = (const float*)d_in[5];
  const float* hc_bih   = (const float*)d_in[6];
  const float* hc_Whh   = (const float*)d_in[7];
  const float* hc_lng   = (const float*)d_in[8];
  const float* hc_lnb   = (const float*)d_in[9];
  const float* hc_lncg  = (const float*)d_in[10];
  const float* hc_lncb  = (const float*)d_in[11];
  const float* Wph      = (const float*)d_in[12];
  const float* bph      = (const float*)d_in[13];
  const float* Wpx      = (const float*)d_in[14];
  const float* bpx      = (const float*)d_in[15];
  const float* Wpb      = (const float*)d_in[16];
  const float* Wsh      = (const float*)d_in[17];
  const float* Wsx      = (const float*)d_in[18];
  const float* Wsb      = (const float*)d_in[19];
  const float* Wih      = (const float*)d_in[20];
  const float* Whh      = (const float*)d_in[21];
  const float* bias     = (const float*)d_in[22];
  const float* ln_g     = (const float*)d_in[23];
  const float* ln_b     = (const float*)d_in[24];
  const float* lnc_g    = (const float*)d_in[25];
  const float* lnc_b    = (const float*)d_in[26];

  float* out = (float*)d_out;
  float* ws  = (float*)d_ws;
  float* ws_v     = ws;                 // 512*1024
  float* ws_P     = ws + 524288;        // 512*768
  float* ws_gates = ws + 917504;        // 512*8192
  const float* nhh = out + 2097152;     // new_hyper_h region of d_out

  k1_hyper_gemm<<<dim3(32, 16), 256, 0, stream>>>(x, h, hyper_h, hc_Wih, hc_Whh, hc_bih, ws_v);
  k2_hyper_cell<<<128, 256, 0, stream>>>(ws_v, hyper_c, hc_lng, hc_lnb, hc_lncg, hc_lncb, out);
  k3_pmat<<<dim3(12, 8), 256, 0, stream>>>(nhh, Wph, Wpx, Wpb, bph, bpx, ws_P);
  k4_gates<<<512, 256, 0, stream>>>(x, h, Wih, Whh, bias, ws_P, Wsh, Wsx, Wsb, ws_gates);
  k5_cell<<<512, 256, 0, stream>>>(ws_gates, c, ln_g, ln_b, lnc_g, lnc_b, out);
}